// Round 12
// baseline (347.618 us; speedup 1.0000x reference)
//
#include <hip/hip_runtime.h>
#include <hip/hip_cooperative_groups.h>
#include <hip/hip_bf16.h>

namespace cg = cooperative_groups;

#define H_IMG 224
#define W_IMG 224
#define B_ 4
#define C_ 256
#define M_ 1024
#define N_ 16384
#define HW_ (H_IMG * W_IMG)
#define OH_ 56
#define OW_ 56
#define NBLK_ (OH_ * OW_)        // 3136 pool blocks per batch
#define NBINS_ (B_ * NBLK_)      // 12544 total bins
#define NT_ (B_ * N_)            // 65536 total points
#define SEG_ 32                  // max points per gather segment
#define MAXSEG_ (NBINS_ + NT_ / SEG_)   // 14592 upper bound
#define KS_ 8                    // center-dim slices in top3
#define MC_ (M_ / KS_)           // 128 centers per slice
#define PTS_ 128                 // points per top3 tile
#define NTILE3_ (B_ * N_ / PTS_) // 512 top3 tiles
// contiguous zero region: tmp + cnt + binCnt + binFill + segTotal
#define ZTOT_ (NBINS_ * C_ + B_ * HW_ + 2 * NBINS_ + 1)
#define SCAN_PER_ ((NBINS_ + 1023) / 1024)   // 13

struct Params {
    const float* xyz; const float* points; const float* centers; const float* K;
    float* out;
    float* XT; int4* idP; float4* wP; int4* segs;
    float* tmp; float* cnt; int* binCnt; int* binFill; int* segTotal;
    int* pixA; int* idA; float* wA; int* binOff;
    float* zeroRegion;
};

// ONE cooperative kernel, 6 phases split by grid.sync():
//  A zero+transpose | B top3 (full occupancy) | C scan+segemit (block 0)
//  D pack | E segment gather | F untranspose
// R11 postmortem: 6 inter-kernel launch gaps + top3 at 1 block/CU (50% occ)
// were the cost. 512 blocks x 1024 thr = exactly 2 blocks/CU (launch_bounds
// caps VGPR<=64; LDS 40KB x2 <= 160KB).
__global__ __launch_bounds__(1024, 8) void mega_kernel(Params P)
{
#pragma clang fp contract(off)
    cg::grid_group grd = cg::this_grid();
    const int t   = threadIdx.x;
    const int bid = blockIdx.x;
    const int G   = gridDim.x;

    // 40KB shared, phase-partitioned views
    __shared__ __attribute__((aligned(16))) char smraw[40960];
    float  (*tile)[33] = reinterpret_cast<float (*)[33]>(smraw);      // A/F: 4.2KB
    float4* cen  = reinterpret_cast<float4*>(smraw);                  // B: [1024] 16KB
    float*  pd   = reinterpret_cast<float*>(smraw + 16384);           // B: [8][128][3] 12KB
    int*    pi   = reinterpret_cast<int*>(smraw + 28672);             // B: 12KB
    int*    partK= reinterpret_cast<int*>(smraw);                     // C: 4KB
    int*    partS= reinterpret_cast<int*>(smraw + 4096);              // C: 4KB
    int4*   sIdA = reinterpret_cast<int4*>(smraw + 8192);             // E: 4x32x16B
    float4* sWA  = reinterpret_cast<float4*>(smraw + 8192 + 4 * SEG_ * 16);

    // ================= Phase A: fused zeroing + feature transpose ==========
    {
        int gtid = bid * 1024 + t;
        for (int i = gtid; i < ZTOT_; i += G * 1024) P.zeroRegion[i] = 0.0f;
        int tx = t & 31, ty = t >> 5;
        for (int tid2 = bid; tid2 < 1024; tid2 += G) {   // 4 b x 8 c x 32 m tiles
            int b  = tid2 >> 8;
            int r  = tid2 & 255;
            int c0 = (r >> 5) * 32;
            int m0 = (r & 31) * 32;
            __syncthreads();
            tile[ty][tx] = P.xyz[(b * C_ + c0 + ty) * M_ + m0 + tx];
            __syncthreads();
            P.XT[(b * M_ + m0 + ty) * C_ + c0 + tx] = tile[tx][ty];
        }
    }
    grd.sync();   // zeroed cnt/binCnt/tmp visible before phase-B atomics

    // ================= Phase B: top-3 NN ===================================
    // NUMERICS LOCKED (R7): dot = ((pz*cz)+(py*cy))+(px*cx) separate mul/add
    // (np einsum descending tail); p2/c2 ascending; d=(p2+c2)-2*dot; strict-<
    // stable insert; lex (d,idx) merge == global stable top-3. DO NOT TOUCH.
    for (int tid3 = bid; tid3 < NTILE3_; tid3 += G) {
        int b     = tid3 >> 7;           // 128 tiles per batch
        int nbase = (tid3 & 127) * PTS_;
        __syncthreads();                 // prev iteration's merge done
        {   // stage 1024 centers, one per thread
            const float* cb = P.centers + (size_t)(b * M_ + t) * 3;
            float cx = cb[0], cy = cb[1], cz = cb[2];
            float c2 = ((cx * cx) + (cy * cy)) + (cz * cz);  // np.sum ascending
            cen[t] = make_float4(cx, cy, cz, c2);
        }
        __syncthreads();

        int pl = t & 127;                // point lane
        int s  = t >> 7;                 // slice
        int g0 = b * N_ + nbase + pl;
        const float* pp = P.points + (size_t)g0 * 3;
        float px = pp[0], py = pp[1], pz = pp[2];
        float p2 = ((px * px) + (py * py)) + (pz * pz);      // np.sum ascending

        float d0 = 1e30f, d1 = 1e30f, d2v = 1e30f;
        int   i0 = 0, i1 = 0, i2 = 0;
        int mbase = s * MC_;
#pragma unroll 4
        for (int j = 0; j < MC_; ++j) {
            int m = mbase + j;
            float4 cc = cen[m];                  // uniform: LDS broadcast
            float dot = ((pz * cc.z) + (py * cc.y)) + (px * cc.x); // np tail
            float d   = (p2 + cc.w) - (2.0f * dot);
            if (d < d2v) {                       // strict <: lowest idx wins
                if (d < d1) {
                    d2v = d1; i2 = i1;
                    if (d < d0) { d1 = d0; i1 = i0; d0 = d; i0 = m; }
                    else        { d1 = d;  i1 = m; }
                } else { d2v = d; i2 = m; }
            }
        }
        int pb = (s * PTS_ + pl) * 3;
        pd[pb] = d0;  pd[pb + 1] = d1;  pd[pb + 2] = d2v;
        pi[pb] = i0;  pi[pb + 1] = i1;  pi[pb + 2] = i2;
        __syncthreads();

        if (t < PTS_) {
            // merge 24 candidates, full lexicographic (d, idx)
            float md0 = 1e30f, md1 = 1e30f, md2 = 1e30f;
            int   mi0 = M_,    mi1 = M_,    mi2 = M_;
#pragma unroll
            for (int ss = 0; ss < KS_; ++ss)
#pragma unroll
                for (int j = 0; j < 3; ++j) {
                    float dd = pd[(ss * PTS_ + t) * 3 + j];
                    int   ii = pi[(ss * PTS_ + t) * 3 + j];
                    if ((dd < md2) || (dd == md2 && ii < mi2)) {
                        if ((dd < md1) || (dd == md1 && ii < mi1)) {
                            md2 = md1; mi2 = mi1;
                            if ((dd < md0) || (dd == md0 && ii < mi0)) {
                                md1 = md0; mi1 = mi0; md0 = dd; mi0 = ii;
                            } else { md1 = dd; mi1 = ii; }
                        } else { md2 = dd; mi2 = ii; }
                    }
                }

            float w0 = 1.0f / (md0 + 1e-8f);
            float w1 = 1.0f / (md1 + 1e-8f);
            float w2 = 1.0f / (md2 + 1e-8f);
            float ws = (w0 + w1) + w2;
            w0 /= ws; w1 /= ws; w2 /= ws;

            int g = b * N_ + nbase + t;
            const float* pq = P.points + (size_t)g * 3;
            float qx = pq[0], qy = pq[1], qz = pq[2];
            // projection: order-invariant (single add of 2 products; 0*py exact)
            float fx = P.K[0], cxk = P.K[2], fy = P.K[4], cyk = P.K[5];
            float u_num = (cxk * qz) + (fx * qx);
            float v_num = (cyk * qz) + (fy * qy);
            float zc    = fmaxf(qz, 1e-8f);
            float u = floorf(u_num / zc);
            float v = floorf(v_num / zc);
            int ui = (int)fminf(fmaxf(u, 0.0f), (float)(W_IMG - 1));
            int vi = (int)fminf(fmaxf(v, 0.0f), (float)(H_IMG - 1));
            int pix = vi * W_IMG + ui;

            P.pixA[g] = pix;
            P.idA[g] = mi0; P.idA[g + NT_] = mi1; P.idA[g + 2 * NT_] = mi2;
            P.wA [g] = w0;  P.wA [g + NT_] = w1;  P.wA [g + 2 * NT_] = w2;
            atomicAdd(&P.cnt[b * HW_ + pix], 1.0f);
            int bin = b * NBLK_ + (vi >> 2) * OW_ + (ui >> 2);
            atomicAdd(&P.binCnt[bin], 1);
        }
    }
    grd.sync();

    // ================= Phase C: dual scan + deterministic seg emit =========
    if (bid == 0) {
        int base = t * SCAN_PER_;
        int localK[SCAN_PER_], localS[SCAN_PER_];
        int sk = 0, sn = 0;
#pragma unroll
        for (int j = 0; j < SCAN_PER_; ++j) {
            int idx = base + j;
            int k = (idx < NBINS_) ? P.binCnt[idx] : 0;
            int ns = 0;
            if (idx < NBINS_) { ns = (k + SEG_ - 1) / SEG_; if (ns == 0) ns = 1; }
            localK[j] = sk; localS[j] = sn;
            sk += k; sn += ns;
        }
        partK[t] = sk; partS[t] = sn;
        __syncthreads();
        for (int ofs = 1; ofs < 1024; ofs <<= 1) {
            int vK = (t >= ofs) ? partK[t - ofs] : 0;
            int vS = (t >= ofs) ? partS[t - ofs] : 0;
            __syncthreads();
            partK[t] += vK; partS[t] += vS;
            __syncthreads();
        }
        int exK = (t == 0) ? 0 : partK[t - 1];
        int exS = (t == 0) ? 0 : partS[t - 1];
#pragma unroll
        for (int j = 0; j < SCAN_PER_; ++j) {
            int idx = base + j;
            if (idx >= NBINS_) continue;
            int off = exK + localK[j];
            int sb  = exS + localS[j];
            P.binOff[idx] = off;
            int k = P.binCnt[idx];
            int nseg = (k + SEG_ - 1) / SEG_; if (nseg == 0) nseg = 1;
            for (int q = 0; q < nseg; ++q) {
                int len = k - q * SEG_;
                len = (len < 0) ? 0 : ((len > SEG_) ? SEG_ : len);
                P.segs[sb + q] = make_int4(idx, off + q * SEG_, len, nseg);
            }
        }
        if (t == 0) P.segTotal[0] = partS[1023];
    }
    grd.sync();

    // ================= Phase D: pack into bin order, pre-scale weights =====
    for (int g = bid * 1024 + t; g < NT_; g += G * 1024) {
        int b = g >> 14;
        int pix = P.pixA[g];
        int u = pix % W_IMG, v = pix / W_IMG;
        int bin = b * NBLK_ + (v >> 2) * OW_ + (u >> 2);
        int pos = atomicAdd(&P.binFill[bin], 1);
        int dst = P.binOff[bin] + pos;
        float sc = 0.0625f / fmaxf(P.cnt[b * HW_ + pix], 1.0f);
        P.idP[dst] = make_int4(P.idA[g], P.idA[g + NT_], P.idA[g + 2 * NT_], b);
        P.wP[dst]  = make_float4(P.wA[g] * sc, P.wA[g + NT_] * sc,
                                 P.wA[g + 2 * NT_] * sc, 0.0f);
    }
    grd.sync();

    // ================= Phase E: per-segment gather into bin-major tmp ======
    {
        int segTot = P.segTotal[0];
        int sub = t >> 8, c = t & 255;          // 4 x 256-thread subgroups
        int4*   mysId = sIdA + sub * SEG_;
        float4* mysW  = sWA  + sub * SEG_;
        for (int base2 = bid * 4; base2 < segTot; base2 += G * 4) {
            int sid = base2 + sub;
            bool active = (sid < segTot);
            int4 sg = make_int4(0, 0, 0, 1);
            if (active) sg = P.segs[sid];
            __syncthreads();                    // prev round LDS reads done
            if (active && c < sg.z) { mysId[c] = P.idP[sg.y + c];
                                      mysW[c]  = P.wP[sg.y + c]; }
            __syncthreads();
            if (active) {
                int bin = sg.x;
                int b = bin / NBLK_;
                const float* XTb = P.XT + (size_t)b * (M_ * C_);
                float acc = 0.0f;
                for (int j = 0; j < sg.z; ++j) {
                    int4 id = mysId[j]; float4 w = mysW[j];
                    acc = fmaf(w.x, XTb[id.x * C_ + c],
                          fmaf(w.y, XTb[id.y * C_ + c],
                          fmaf(w.z, XTb[id.z * C_ + c], acc)));
                }
                float* dst = &P.tmp[(size_t)bin * C_ + c];
                if (sg.w == 1) *dst = acc;       // covers empty bins (acc=0)
                else           atomicAdd(dst, acc);  // tmp pre-zeroed (A)
            }
        }
    }
    grd.sync();

    // ================= Phase F: untranspose tmp (B,NBLK,C) -> out ==========
    {
        int tx = t & 31, ty = t >> 5;
        for (int tid6 = bid; tid6 < 3136; tid6 += G) {   // 4 b x 98 n x 8 c
            int b  = tid6 / 784;
            int r  = tid6 - b * 784;
            int c0 = (r & 7) * 32;
            int n0 = (r >> 3) * 32;
            __syncthreads();
            tile[ty][tx] = P.tmp[((size_t)b * NBLK_ + n0 + ty) * C_ + c0 + tx];
            __syncthreads();
            P.out[((size_t)(b * C_ + c0 + ty)) * NBLK_ + n0 + tx] = tile[tx][ty];
        }
    }
}

extern "C" void kernel_launch(void* const* d_in, const int* in_sizes, int n_in,
                              void* d_out, int out_size, void* d_ws, size_t ws_size,
                              hipStream_t stream)
{
    Params P;
    P.xyz     = (const float*)d_in[0];
    P.points  = (const float*)d_in[1];
    P.centers = (const float*)d_in[2];
    P.K       = (const float*)d_in[3];
    P.out     = (float*)d_out;

    // workspace layout (~21.7 MB), zero region contiguous: tmp..segTotal
    float*  XT       = (float*)d_ws;                         // 4 MB
    int4*   idP      = (int4*)(XT + (size_t)B_ * M_ * C_);   // 1 MB
    float4* wP       = (float4*)(idP + NT_);                 // 1 MB
    int4*   segs     = (int4*)(wP + NT_);                    // 228 KB
    float*  tmp      = (float*)(segs + MAXSEG_);             // 12.8 MB
    float*  cnt      = tmp + (size_t)NBINS_ * C_;            // 784 KB
    int*    binCnt   = (int*)(cnt + (size_t)B_ * HW_);       // 50 KB
    int*    binFill  = binCnt + NBINS_;                      // 50 KB
    int*    segTotal = binFill + NBINS_;                     // 4 B
    int*    pixA     = segTotal + 1;                         // 256 KB
    int*    idA      = pixA + NT_;                           // 768 KB
    float*  wA       = (float*)(idA + 3 * NT_);              // 768 KB
    int*    binOff   = (int*)(wA + 3 * NT_);                 // 50 KB

    P.XT = XT; P.idP = idP; P.wP = wP; P.segs = segs; P.tmp = tmp;
    P.cnt = cnt; P.binCnt = binCnt; P.binFill = binFill; P.segTotal = segTotal;
    P.pixA = pixA; P.idA = idA; P.wA = wA; P.binOff = binOff;
    P.zeroRegion = tmp;   // tmp..segTotal contiguous, ZTOT_ floats

    int maxB = 0;
    if (hipOccupancyMaxActiveBlocksPerMultiprocessor(
            &maxB, reinterpret_cast<const void*>(mega_kernel), 1024, 0)
        != hipSuccess || maxB < 1) maxB = 1;
    int G = maxB * 256;
    if (G > NTILE3_) G = NTILE3_;   // 512: one top3 tile per block

    void* kargs[] = { &P };
    hipLaunchCooperativeKernel(reinterpret_cast<const void*>(mega_kernel),
                               dim3(G), dim3(1024), kargs, 0, stream);
}

// Round 14
// 186.877 us; speedup vs baseline: 1.8601x; 1.8601x over previous
//
#include <hip/hip_runtime.h>
#include <hip/hip_bf16.h>

#define H_IMG 224
#define W_IMG 224
#define B_ 4
#define C_ 256
#define M_ 1024
#define N_ 16384
#define HW_ (H_IMG * W_IMG)
#define OH_ 56
#define OW_ 56
#define NBLK_ (OH_ * OW_)        // 3136 pool blocks per batch
#define NBINS_ (B_ * NBLK_)      // 12544 total bins
#define NT_ (B_ * N_)            // 65536 total points
#define SEG_ 32                  // max points per gather segment
#define MAXSEG_ (NBINS_ + NT_ / SEG_)   // 14592 upper bound
#define KS_ 8                    // center-dimension slices in top3
#define MC_ (M_ / KS_)           // 128 centers per slice
#define PTS_ 128                 // points per top3 block
// contiguous zero region: tmp + cnt + binCnt + binFill + segTotal
#define ZTOT_ (NBINS_ * C_ + B_ * HW_ + 2 * NBINS_ + 1)

// ------- Kernel A: transpose xyz_feats (B,C,M)->XT (B,M,C) + fused zeroing -
__global__ __launch_bounds__(1024) void transpose_kernel(
    const float* __restrict__ xyz, float* __restrict__ XT,
    float* __restrict__ zeroRegion)
{
    __shared__ float tile[32][33];
    int b  = blockIdx.z;
    int c0 = blockIdx.x * 32;
    int m0 = blockIdx.y * 32;
    int tx = threadIdx.x, ty = threadIdx.y;
    int flat = ((blockIdx.z * gridDim.y + blockIdx.y) * gridDim.x + blockIdx.x)
               * 1024 + ty * 32 + tx;
    for (int i = flat; i < ZTOT_; i += 1024 * 1024) zeroRegion[i] = 0.0f;
    tile[ty][tx] = xyz[(b * C_ + c0 + ty) * M_ + m0 + tx];
    __syncthreads();
    XT[(b * M_ + m0 + ty) * C_ + c0 + tx] = tile[tx][ty];
}

// -------- Kernel B: top-3 NN, 512 blocks x (128 pts x 8 slices) ------------
// NUMERICS LOCKED (R7 pass): np ref einsum tail is DESCENDING-index separate
// mul/add: dot = ((pz*cz)+(py*cy))+(px*cx); p2/c2 ascending; d=(p2+c2)-2*dot;
// contract(off); stable top-3 (lowest index on exact ties); projection
// order-invariant. DO NOT change any decision arithmetic.
// R12 postmortem: mega-kernel reverted (grid.sync+VGPR cap stalls). This
// round: (a) 512 blocks = 2 blocks/CU = 32 waves/CU (R11 was 50% cap);
// (b) branchy insert -> stable sorted-insert MIN/MAX NETWORK:
//     nd0=min(d,d0), l0=max(d,d0); idx via (d<d0) cndmask; repeat vs d1, d2.
//     Strict < keeps the incumbent (lower scan index) on exact ties at every
//     boundary => selected SET == stable insertion's. Within-triple order of
//     equal-d entries may differ, but equal d => equal w, and the lex-(d,idx)
//     merge over the 24-candidate multiset is order-independent => final
//     (idx,weight) set bit-identical to R11. ~13 insert-ops/iter vs ~25.
__global__ __launch_bounds__(1024, 8) void top3_kernel(
    const float* __restrict__ points, const float* __restrict__ centers,
    const float* __restrict__ Kmat,
    int* __restrict__ pixA, int* __restrict__ idA, float* __restrict__ wA,
    float* __restrict__ cnt, int* __restrict__ binCnt)
{
#pragma clang fp contract(off)
    __shared__ float4 cen[M_];            // 16 KB
    __shared__ float  pd[KS_][PTS_][3];   // 12 KB partial distances
    __shared__ int    pi[KS_][PTS_][3];   // 12 KB partial indices
    int b     = blockIdx.y;
    int t     = threadIdx.x;
    int pl    = t & 127;                  // point lane
    int s     = t >> 7;                   // slice
    int nbase = blockIdx.x * PTS_;

    {   // stage centers: one per thread (t in [0,1024) == M_)
        const float* cb = centers + (size_t)(b * M_ + t) * 3;
        float cx = cb[0], cy = cb[1], cz = cb[2];
        float c2 = ((cx * cx) + (cy * cy)) + (cz * cz);   // np.sum ascending
        cen[t] = make_float4(cx, cy, cz, c2);
    }
    __syncthreads();

    int g0 = b * N_ + nbase + pl;
    const float* pp = points + (size_t)g0 * 3;
    float px = pp[0], py = pp[1], pz = pp[2];
    float p2 = ((px * px) + (py * py)) + (pz * pz);       // np.sum ascending

    float d0 = 1e30f, d1 = 1e30f, d2v = 1e30f;
    int   i0 = 0, i1 = 0, i2 = 0;
    int mbase = s * MC_;
#pragma unroll 4
    for (int j = 0; j < MC_; ++j) {
        int m = mbase + j;
        float4 cc = cen[m];               // uniform in wave: LDS broadcast
        float dot = ((pz * cc.z) + (py * cc.y)) + (px * cc.x); // np tail order
        float d   = (p2 + cc.w) - (2.0f * dot);
        // stage 0 vs rank0
        bool  c0  = d < d0;
        float l0  = fmaxf(d, d0);         // loser value
        int   li0 = c0 ? i0 : m;          // loser idx (incumbent wins tie)
        d0 = fminf(d, d0);
        i0 = c0 ? m : i0;
        // stage 1: loser vs rank1
        bool  c1  = l0 < d1;
        float l1  = fmaxf(l0, d1);
        int   li1 = c1 ? i1 : li0;
        d1 = fminf(l0, d1);
        i1 = c1 ? li0 : i1;
        // stage 2: loser vs rank2 (max dropped)
        bool  c2  = l1 < d2v;
        d2v = fminf(l1, d2v);
        i2  = c2 ? li1 : i2;
    }
    pd[s][pl][0] = d0;  pd[s][pl][1] = d1;  pd[s][pl][2] = d2v;
    pi[s][pl][0] = i0;  pi[s][pl][1] = i1;  pi[s][pl][2] = i2;
    __syncthreads();

    if (t < PTS_) {
        // merge 24 candidates, full lexicographic (d, idx): order-independent
        float md0 = 1e30f, md1 = 1e30f, md2 = 1e30f;
        int   mi0 = M_,    mi1 = M_,    mi2 = M_;
#pragma unroll
        for (int ss = 0; ss < KS_; ++ss)
#pragma unroll
            for (int j = 0; j < 3; ++j) {
                float dd = pd[ss][t][j];
                int   ii = pi[ss][t][j];
                if ((dd < md2) || (dd == md2 && ii < mi2)) {
                    if ((dd < md1) || (dd == md1 && ii < mi1)) {
                        md2 = md1; mi2 = mi1;
                        if ((dd < md0) || (dd == md0 && ii < mi0)) {
                            md1 = md0; mi1 = mi0; md0 = dd; mi0 = ii;
                        } else { md1 = dd; mi1 = ii; }
                    } else { md2 = dd; mi2 = ii; }
                }
            }

        float w0 = 1.0f / (md0 + 1e-8f);
        float w1 = 1.0f / (md1 + 1e-8f);
        float w2 = 1.0f / (md2 + 1e-8f);
        float ws = (w0 + w1) + w2;
        w0 /= ws; w1 /= ws; w2 /= ws;

        int g = b * N_ + nbase + t;
        const float* pq = points + (size_t)g * 3;
        float qx = pq[0], qy = pq[1], qz = pq[2];
        // projection: order-invariant (single add of two products; 0*py exact)
        float fx = Kmat[0], cxk = Kmat[2], fy = Kmat[4], cyk = Kmat[5];
        float u_num = (cxk * qz) + (fx * qx);
        float v_num = (cyk * qz) + (fy * qy);
        float zc    = fmaxf(qz, 1e-8f);
        float u = floorf(u_num / zc);
        float v = floorf(v_num / zc);
        int ui = (int)fminf(fmaxf(u, 0.0f), (float)(W_IMG - 1));
        int vi = (int)fminf(fmaxf(v, 0.0f), (float)(H_IMG - 1));
        int pix = vi * W_IMG + ui;

        pixA[g] = pix;
        idA[g]           = mi0; idA[g + NT_]     = mi1; idA[g + 2 * NT_] = mi2;
        wA [g]           = w0;  wA [g + NT_]     = w1;  wA [g + 2 * NT_] = w2;
        atomicAdd(&cnt[b * HW_ + pix], 1.0f);
        int bin = b * NBLK_ + (vi >> 2) * OW_ + (ui >> 2);
        atomicAdd(&binCnt[bin], 1);
    }
}

// ------- Kernel S: dual exclusive scan (k, nseg) + deterministic seg emit --
__global__ __launch_bounds__(1024) void scan_kernel(
    const int* __restrict__ binCnt, int* __restrict__ binOff,
    int4* __restrict__ segs, int* __restrict__ segTotal)
{
    const int PER = (NBINS_ + 1023) / 1024;   // 13
    __shared__ int partK[1024], partS[1024];
    int t = threadIdx.x;
    int base = t * PER;
    int localK[PER], localS[PER];
    int sk = 0, sn = 0;
#pragma unroll
    for (int j = 0; j < PER; ++j) {
        int idx = base + j;
        int k  = (idx < NBINS_) ? binCnt[idx] : 0;
        int ns = 0;
        if (idx < NBINS_) { ns = (k + SEG_ - 1) / SEG_; if (ns == 0) ns = 1; }
        localK[j] = sk; localS[j] = sn;
        sk += k; sn += ns;
    }
    partK[t] = sk; partS[t] = sn;
    __syncthreads();
    for (int ofs = 1; ofs < 1024; ofs <<= 1) {
        int vK = (t >= ofs) ? partK[t - ofs] : 0;
        int vS = (t >= ofs) ? partS[t - ofs] : 0;
        __syncthreads();
        partK[t] += vK; partS[t] += vS;
        __syncthreads();
    }
    int exK = (t == 0) ? 0 : partK[t - 1];
    int exS = (t == 0) ? 0 : partS[t - 1];
#pragma unroll
    for (int j = 0; j < PER; ++j) {
        int idx = base + j;
        if (idx >= NBINS_) continue;
        int off = exK + localK[j];
        int sb  = exS + localS[j];
        binOff[idx] = off;
        int k = binCnt[idx];
        int nseg = (k + SEG_ - 1) / SEG_; if (nseg == 0) nseg = 1;
        for (int q = 0; q < nseg; ++q) {
            int len = k - q * SEG_;
            len = (len < 0) ? 0 : ((len > SEG_) ? SEG_ : len);
            segs[sb + q] = make_int4(idx, off + q * SEG_, len, nseg);
        }
    }
    if (t == 0) segTotal[0] = partS[1023];
}

// ---------------- Kernel P: pack points into bin order, pre-scale weights --
__global__ __launch_bounds__(256) void pack_kernel(
    const int* __restrict__ pixA, const int* __restrict__ idA,
    const float* __restrict__ wA, const float* __restrict__ cnt,
    const int* __restrict__ binOff, int* __restrict__ binFill,
    int4* __restrict__ idP, float4* __restrict__ wP)
{
    int g = blockIdx.x * 256 + threadIdx.x;
    int b = g >> 14;                     // N_ = 16384
    int pix = pixA[g];
    int u = pix % W_IMG, v = pix / W_IMG;
    int bin = b * NBLK_ + (v >> 2) * OW_ + (u >> 2);
    int pos = atomicAdd(&binFill[bin], 1);
    int dst = binOff[bin] + pos;
    float s = 0.0625f / fmaxf(cnt[b * HW_ + pix], 1.0f);
    idP[dst] = make_int4(idA[g], idA[g + NT_], idA[g + 2 * NT_], b);
    wP[dst]  = make_float4(wA[g] * s, wA[g + NT_] * s, wA[g + 2 * NT_] * s, 0.0f);
}

// ---------------- Kernel G: per-segment gather-reduce into bin-major tmp ---
// Bin-major stores: 64 consecutive lanes = contiguous 1KB => zero inflation.
// 2 accumulators break the serial FMA chain (continuous-only reorder).
__global__ __launch_bounds__(256) void gather_kernel(
    const float* __restrict__ XT, const int4* __restrict__ segs,
    const int* __restrict__ segTotal, const int4* __restrict__ idP,
    const float4* __restrict__ wP, float* __restrict__ tmp)
{
    int sid = blockIdx.x;
    if (sid >= segTotal[0]) return;
    int4 sg   = segs[sid];
    int bin   = sg.x, start = sg.y, len = sg.z, nseg = sg.w;
    int b     = bin / NBLK_;
    int c     = threadIdx.x;

    __shared__ int4   sId[SEG_];
    __shared__ float4 sW [SEG_];
    if (c < len) { sId[c] = idP[start + c]; sW[c] = wP[start + c]; }
    __syncthreads();

    const float* XTb = XT + (size_t)b * (M_ * C_);
    float accA = 0.0f, accB = 0.0f;
    int j = 0;
    for (; j + 1 < len; j += 2) {
        int4 ia = sId[j];     float4 wa = sW[j];
        int4 ib = sId[j + 1]; float4 wb = sW[j + 1];
        accA = fmaf(wa.x, XTb[ia.x * C_ + c],
               fmaf(wa.y, XTb[ia.y * C_ + c],
               fmaf(wa.z, XTb[ia.z * C_ + c], accA)));
        accB = fmaf(wb.x, XTb[ib.x * C_ + c],
               fmaf(wb.y, XTb[ib.y * C_ + c],
               fmaf(wb.z, XTb[ib.z * C_ + c], accB)));
    }
    if (j < len) {
        int4 ia = sId[j]; float4 wa = sW[j];
        accA = fmaf(wa.x, XTb[ia.x * C_ + c],
               fmaf(wa.y, XTb[ia.y * C_ + c],
               fmaf(wa.z, XTb[ia.z * C_ + c], accA)));
    }
    float acc = accA + accB;

    float* dst = &tmp[(size_t)bin * C_ + c];
    if (nseg == 1) *dst = acc;            // covers empty bins (acc = 0)
    else           atomicAdd(dst, acc);   // tmp pre-zeroed in transpose_kernel
}

// ---------------- Kernel U: untranspose tmp (B,NBLK,C) -> out (B,C,NBLK) ---
__global__ __launch_bounds__(1024) void untranspose_kernel(
    const float* __restrict__ tmp, float* __restrict__ out)
{
    __shared__ float tile[32][33];
    int b  = blockIdx.z;
    int n0 = blockIdx.x * 32;   // NBLK_/32 = 98
    int c0 = blockIdx.y * 32;   // C_/32 = 8
    int tx = threadIdx.x, ty = threadIdx.y;
    tile[ty][tx] = tmp[((size_t)b * NBLK_ + n0 + ty) * C_ + c0 + tx];
    __syncthreads();
    out[((size_t)(b * C_ + c0 + ty)) * NBLK_ + n0 + tx] = tile[tx][ty];
}

extern "C" void kernel_launch(void* const* d_in, const int* in_sizes, int n_in,
                              void* d_out, int out_size, void* d_ws, size_t ws_size,
                              hipStream_t stream)
{
    const float* xyz_feats = (const float*)d_in[0];  // (B,C,M)
    const float* points    = (const float*)d_in[1];  // (B,N,3)
    const float* centers   = (const float*)d_in[2];  // (B,M,3)
    const float* Kmat      = (const float*)d_in[3];  // (3,3)

    float* out = (float*)d_out;

    // workspace layout (~21.7 MB)
    float*  XT       = (float*)d_ws;                         // 4 MB
    int4*   idP      = (int4*)(XT + (size_t)B_ * M_ * C_);   // 1 MB
    float4* wP       = (float4*)(idP + NT_);                 // 1 MB
    int4*   segs     = (int4*)(wP + NT_);                    // 228 KB
    float*  tmp      = (float*)(segs + MAXSEG_);             // 12.8 MB (zero rgn)
    float*  cnt      = tmp + (size_t)NBINS_ * C_;            // 784 KB
    int*    binCnt   = (int*)(cnt + (size_t)B_ * HW_);       // 50 KB
    int*    binFill  = binCnt + NBINS_;                      // 50 KB
    int*    segTotal = binFill + NBINS_;                     // 4 B
    int*    pixA     = segTotal + 1;                         // 256 KB
    int*    idA      = pixA + NT_;                           // 768 KB
    float*  wA       = (float*)(idA + 3 * NT_);              // 768 KB
    int*    binOff   = (int*)(wA + 3 * NT_);                 // 50 KB

    dim3 tb(32, 32);
    dim3 tg(C_ / 32, M_ / 32, B_);
    transpose_kernel<<<tg, tb, 0, stream>>>(xyz_feats, XT, tmp);

    dim3 bg(N_ / PTS_, B_);   // 128 x 4 = 512 blocks, 2 blocks/CU
    top3_kernel<<<bg, 1024, 0, stream>>>(points, centers, Kmat,
                                         pixA, idA, wA, cnt, binCnt);

    scan_kernel<<<1, 1024, 0, stream>>>(binCnt, binOff, segs, segTotal);

    pack_kernel<<<NT_ / 256, 256, 0, stream>>>(pixA, idA, wA, cnt,
                                               binOff, binFill, idP, wP);

    gather_kernel<<<MAXSEG_, 256, 0, stream>>>(XT, segs, segTotal,
                                               idP, wP, tmp);

    dim3 ug(NBLK_ / 32, C_ / 32, B_);
    untranspose_kernel<<<ug, tb, 0, stream>>>(tmp, out);
}